// Round 4
// baseline (252.129 us; speedup 1.0000x reference)
//
#include <hip/hip_runtime.h>
#include <math.h>

typedef _Float16 half4_t __attribute__((ext_vector_type(4)));
typedef _Float16 half8_t __attribute__((ext_vector_type(8)));
typedef __fp16   fp16x2  __attribute__((ext_vector_type(2)));
typedef float    f32x4   __attribute__((ext_vector_type(4)));

#define B_   32
#define NQ_  16384
#define NK_  31
#define DM_  64
#define BLK_PER_B 64      // 2048 blocks total
#define ITERS 4           // tiles per wave; ALL prefetched at entry
#define KSCALE 0.3606738222635048f   // 0.25 * log2(e): GEMM1 outputs log2-domain scores

static __device__ __forceinline__ half4_t cvt4(f32x4 f) {
  fp16x2 lo = __builtin_amdgcn_cvt_pkrtz(f[0], f[1]);
  fp16x2 hi = __builtin_amdgcn_cvt_pkrtz(f[2], f[3]);
  half4_t r;
  r[0] = (_Float16)lo[0]; r[1] = (_Float16)lo[1];
  r[2] = (_Float16)hi[0]; r[3] = (_Float16)hi[1];
  return r;
}

// ---------------------------------------------------------------------------
// Fused MHA + out-proj. Block = 4 waves, 20 KB LDS for block-invariant frags.
// R3 post-mortem: the 4-deep Q ring never materialized -- VGPR_Count=88 shows
// the scheduler SANK the prefetch loads to their consumers (no fence stopped
// it), so effective prefetch depth stayed 1 and dur stayed ~88us. This
// version loads ALL 4 Q tiles (16 KB/wave) in one burst at kernel entry and
// pins them with sched_barrier(0), a hard scheduler fence. Load latency then
// overlaps the whole mask/K/VW prologue; the main loop is pure compute+store.
// VGPR ~140 is the tell that the block stayed live.
// ---------------------------------------------------------------------------
__global__ __launch_bounds__(256) void attn(
    const float* __restrict__ Q, const float* __restrict__ K,
    const float* __restrict__ V, const unsigned char* __restrict__ mraw,
    const float* __restrict__ W, const float* __restrict__ bout,
    float* __restrict__ out) {
  int b    = blockIdx.x >> 6;             // 64 blocks per batch
  int blk  = blockIdx.x & 63;
  int tid  = threadIdx.x;
  int wave = tid >> 6, lane = tid & 63;
  int lq = lane & 15, quad = lane >> 4;

  // [h][lane] : 16B per lane = {kf_tt0, kf_tt1}
  __shared__ half8_t lds_kf[4][64];
  // [s][pair][lane] : 16B per lane = {vw_dt(2p), vw_dt(2p+1)}
  __shared__ half8_t lds_vw[8][2][64];

  const f32x4 fzero = {0.f, 0.f, 0.f, 0.f};

  int w = blk * 4 + wave;                 // 0..255 within batch
  const float* qrow = Q + ((size_t)b * NQ_ + lq) * DM_ + 4 * quad;

  // ---- burst-load ALL Q tiles; fence so the scheduler cannot sink them ----
  f32x4 qbuf[ITERS][4];
  #pragma unroll
  for (int d = 0; d < ITERS; ++d)
    #pragma unroll
    for (int h = 0; h < 4; ++h)
      qbuf[d][h] =
          *(const f32x4*)(qrow + (size_t)((w + d * 256) * 16) * DM_ + 16 * h);
  __builtin_amdgcn_sched_barrier(0);

  // ---- mask word (per-wave, ballot-based; dtype sniffed from raw bytes) ----
  unsigned mb;
  {
    unsigned char c0 = 0, c1 = 0;
    if (lane < 62) { c0 = mraw[2 * lane]; c1 = mraw[2 * lane + 1]; }
    unsigned long long m3f =
        __ballot(lane < 62 && (c0 == 0x3f || c1 == 0x3f));
    unsigned long long moff =
        __ballot(lane < 62 && ((((2 * lane) & 3) != 0 && c0 != 0) || c1 != 0));
    int mode = m3f ? 2 : (moff ? 0 : 1);
    int nz = 0;
    if (lane < NK_) {
      int idx = b * NK_ + lane;
      nz = (mode == 0) ? (mraw[idx] != 0)
         : (mode == 1) ? (((const int*)mraw)[idx] != 0)
                       : (((const float*)mraw)[idx] != 0.0f);
    }
    mb = (unsigned)__ballot(nz) & 0x7fffffffu;
  }

  // ---- mask bias for GEMM1's C operand (key 31 pad auto-masked) ----
  f32x4 cbias[2];
  #pragma unroll
  for (int tt = 0; tt < 2; ++tt)
    #pragma unroll
    for (int r = 0; r < 4; ++r) {
      int key = 16 * tt + 4 * quad + r;
      cbias[tt][r] = ((mb >> key) & 1u) ? 0.0f : -1e30f;
    }

  // ---- K fragments: wave computes frags f = 2*wave, 2*wave+1 (f=4*tt+h) ----
  #pragma unroll
  for (int j = 0; j < 2; ++j) {
    int f  = wave * 2 + j;
    int tt = f >> 2, h = f & 3;
    int k  = 16 * tt + lq;
    f32x4 fv = fzero;
    if (k < NK_)
      fv = *(const f32x4*)(K + ((size_t)b * NK_ + k) * DM_ + 16 * h + 4 * quad);
    ((half4_t*)&lds_kf[h][lane])[tt] = cvt4(fv * KSCALE);
  }

  // ---- VW^T fragments for dt = wave (8 prologue MFMAs) ----
  {
    half4_t af[8];
    #pragma unroll
    for (int s = 0; s < 8; ++s) {
      int k = 16 * (s & 1) + lq, h = s >> 1;
      f32x4 f = fzero;
      if (k < NK_)
        f = *(const f32x4*)(V + ((size_t)b * NK_ + k) * DM_ + 16 * h + 4 * quad);
      af[s] = cvt4(f);
    }
    half4_t bf[4];
    #pragma unroll
    for (int h = 0; h < 4; ++h) {
      f32x4 f = *(const f32x4*)(W + (16 * wave + lq) * DM_ + 16 * h + 4 * quad);
      bf[h] = cvt4(f);
    }
    #pragma unroll
    for (int s = 0; s < 8; ++s) {
      f32x4 m = __builtin_amdgcn_mfma_f32_16x16x16f16(af[s], bf[s >> 1],
                                                      fzero, 0, 0, 0);
      ((half4_t*)&lds_vw[s][wave >> 1][lane])[wave & 1] = cvt4(m);
    }
  }

  // ---- bias fragments for the epilogue ----
  f32x4 bias[4];
  #pragma unroll
  for (int dt = 0; dt < 4; ++dt)
    bias[dt] = *(const f32x4*)(bout + 16 * dt + 4 * quad);

  __syncthreads();

  // ---- main loop: all Q already in registers; pure compute + store ----
  #pragma unroll
  for (int it = 0; it < ITERS; ++it) {
    half4_t qf[4];
    #pragma unroll
    for (int h = 0; h < 4; ++h) qf[h] = cvt4(qbuf[it][h]);

    // GEMM1 + per-head softmax (log2-domain scores -> exp2)
    half4_t pf[8];
    #pragma unroll
    for (int h = 0; h < 4; ++h) {
      half8_t kk = lds_kf[h][lane];
      half4_t k0 = __builtin_shufflevector(kk, kk, 0, 1, 2, 3);
      half4_t k1 = __builtin_shufflevector(kk, kk, 4, 5, 6, 7);
      f32x4 c0 = __builtin_amdgcn_mfma_f32_16x16x16f16(k0, qf[h], cbias[0], 0, 0, 0);
      f32x4 c1 = __builtin_amdgcn_mfma_f32_16x16x16f16(k1, qf[h], cbias[1], 0, 0, 0);
      f32x4 e0, e1;
      #pragma unroll
      for (int r = 0; r < 4; ++r) {
        e0[r] = __builtin_amdgcn_exp2f(c0[r]);
        e1[r] = __builtin_amdgcn_exp2f(c1[r]);
      }
      float sum = (e0[0] + e0[1]) + (e0[2] + e0[3]) +
                  (e1[0] + e1[1]) + (e1[2] + e1[3]);
      sum += __shfl_xor(sum, 16);
      sum += __shfl_xor(sum, 32);
      float inv = (sum > 0.f) ? __builtin_amdgcn_rcpf(sum) : 0.f;
      pf[2 * h + 0] = cvt4(e0 * inv);
      pf[2 * h + 1] = cvt4(e1 * inv);
    }

    // GEMM2; VW^T frags streamed from LDS (2x ds_read_b128 per s)
    f32x4 acc[4] = {fzero, fzero, fzero, fzero};
    #pragma unroll
    for (int s = 0; s < 8; ++s) {
      half8_t v01 = lds_vw[s][0][lane];
      half8_t v23 = lds_vw[s][1][lane];
      half4_t a0 = __builtin_shufflevector(v01, v01, 0, 1, 2, 3);
      half4_t a1 = __builtin_shufflevector(v01, v01, 4, 5, 6, 7);
      half4_t a2 = __builtin_shufflevector(v23, v23, 0, 1, 2, 3);
      half4_t a3 = __builtin_shufflevector(v23, v23, 4, 5, 6, 7);
      acc[0] = __builtin_amdgcn_mfma_f32_16x16x16f16(a0, pf[s], acc[0], 0, 0, 0);
      acc[1] = __builtin_amdgcn_mfma_f32_16x16x16f16(a1, pf[s], acc[1], 0, 0, 0);
      acc[2] = __builtin_amdgcn_mfma_f32_16x16x16f16(a2, pf[s], acc[2], 0, 0, 0);
      acc[3] = __builtin_amdgcn_mfma_f32_16x16x16f16(a3, pf[s], acc[3], 0, 0, 0);
    }

    // epilogue (plain cached stores)
    int q0 = (w + it * 256) * 16;
    float* obase = out + ((size_t)b * NQ_ + q0 + lq) * DM_ + 4 * quad;
    #pragma unroll
    for (int dt = 0; dt < 4; ++dt)
      *(f32x4*)(obase + 16 * dt) = acc[dt] + bias[dt];
  }
}

extern "C" void kernel_launch(void* const* d_in, const int* in_sizes, int n_in,
                              void* d_out, int out_size, void* d_ws, size_t ws_size,
                              hipStream_t stream) {
  const float*         Q    = (const float*)d_in[0];
  const float*         K    = (const float*)d_in[1];
  const float*         V    = (const float*)d_in[2];
  const unsigned char* mask = (const unsigned char*)d_in[3];
  const float*         W    = (const float*)d_in[4];
  const float*         bo   = (const float*)d_in[5];
  float*               out  = (float*)d_out;

  hipLaunchKernelGGL(attn, dim3(B_ * BLK_PER_B), dim3(256), 0, stream,
                     Q, K, V, mask, W, bo, out);
}

// Round 5
// 247.917 us; speedup vs baseline: 1.0170x; 1.0170x over previous
//
#include <hip/hip_runtime.h>
#include <math.h>

typedef _Float16 half4_t __attribute__((ext_vector_type(4)));
typedef _Float16 half8_t __attribute__((ext_vector_type(8)));
typedef __fp16   fp16x2  __attribute__((ext_vector_type(2)));
typedef float    f32x4   __attribute__((ext_vector_type(4)));

#define B_   32
#define NQ_  16384
#define NK_  31
#define DM_  64
#define BLK_PER_B 64      // 2048 blocks total
#define ITERS 4           // tiles per wave
#define KSCALE 0.3606738222635048f   // 0.25 * log2(e): GEMM1 outputs log2-domain scores

static __device__ __forceinline__ half4_t cvt4(f32x4 f) {
  fp16x2 lo = __builtin_amdgcn_cvt_pkrtz(f[0], f[1]);
  fp16x2 hi = __builtin_amdgcn_cvt_pkrtz(f[2], f[3]);
  half4_t r;
  r[0] = (_Float16)lo[0]; r[1] = (_Float16)lo[1];
  r[2] = (_Float16)hi[0]; r[3] = (_Float16)hi[1];
  return r;
}

// ---------------------------------------------------------------------------
// Fused MHA + out-proj. Block = 4 waves.
// R0-R4 post-mortem: all scheduling/occupancy variants tie at ~90us because
// every Q load and out store used the MFMA fragment layout -- lanes 0..15 at
// 256B stride, 16 scattered 64B segments per instruction, each line touched
// by 4 lane-groups (4x request amplification). That pattern, not scheduling,
// capped HBM at ~2.2 TB/s (the 6.3 TB/s copy ubench is lane-contiguous).
// This version makes ALL global accesses lane-contiguous (lane*16B, the
// ubench pattern) and transposes to/from the fragment layout through a
// per-wave 4KB LDS staging buffer with XOR swizzle (cb ^= row&7) so both
// the strided fragment reads and the contiguous reads are conflict-free.
// Staged tile is 16 VGPR -> compiler's latency scheduler keeps the 1-deep
// prefetch aloft (64-reg rings were pressure-sunk in R3/R4).
// ---------------------------------------------------------------------------
__global__ __launch_bounds__(256) void attn(
    const float* __restrict__ Q, const float* __restrict__ K,
    const float* __restrict__ V, const unsigned char* __restrict__ mraw,
    const float* __restrict__ W, const float* __restrict__ bout,
    float* __restrict__ out) {
  int b    = blockIdx.x >> 6;             // 64 blocks per batch
  int blk  = blockIdx.x & 63;
  int tid  = threadIdx.x;
  int wave = tid >> 6, lane = tid & 63;
  int lq = lane & 15, quad = lane >> 4;

  // [h][lane] : 16B per lane = {kf_tt0, kf_tt1}
  __shared__ half8_t lds_kf[4][64];
  // [s][pair][lane] : 16B per lane = {vw_dt(2p), vw_dt(2p+1)}
  __shared__ half8_t lds_vw[8][2][64];
  // per-wave staging tile: [row][cb] with cb XOR-swizzled by (row&7)
  __shared__ f32x4 stg[4][16][16];

  const f32x4 fzero = {0.f, 0.f, 0.f, 0.f};

  int w = blk * 4 + wave;                 // 0..255 within batch

  // ---- tile-0 Q burst, lane-contiguous (lane*16B) ----
  f32x4 qst[4];
  {
    const float* qb0 = Q + ((size_t)b * NQ_ + (size_t)w * 16) * DM_;
    #pragma unroll
    for (int j = 0; j < 4; ++j)
      qst[j] = *(const f32x4*)(qb0 + j * 256 + lane * 4);
  }

  // ---- mask word (per-wave, ballot-based; dtype sniffed from raw bytes) ----
  unsigned mb;
  {
    unsigned char c0 = 0, c1 = 0;
    if (lane < 62) { c0 = mraw[2 * lane]; c1 = mraw[2 * lane + 1]; }
    unsigned long long m3f =
        __ballot(lane < 62 && (c0 == 0x3f || c1 == 0x3f));
    unsigned long long moff =
        __ballot(lane < 62 && ((((2 * lane) & 3) != 0 && c0 != 0) || c1 != 0));
    int mode = m3f ? 2 : (moff ? 0 : 1);
    int nz = 0;
    if (lane < NK_) {
      int idx = b * NK_ + lane;
      nz = (mode == 0) ? (mraw[idx] != 0)
         : (mode == 1) ? (((const int*)mraw)[idx] != 0)
                       : (((const float*)mraw)[idx] != 0.0f);
    }
    mb = (unsigned)__ballot(nz) & 0x7fffffffu;
  }

  // ---- mask bias for GEMM1's C operand (key 31 pad auto-masked) ----
  f32x4 cbias[2];
  #pragma unroll
  for (int tt = 0; tt < 2; ++tt)
    #pragma unroll
    for (int r = 0; r < 4; ++r) {
      int key = 16 * tt + 4 * quad + r;
      cbias[tt][r] = ((mb >> key) & 1u) ? 0.0f : -1e30f;
    }

  // ---- K fragments: wave computes frags f = 2*wave, 2*wave+1 (f=4*tt+h) ----
  #pragma unroll
  for (int j = 0; j < 2; ++j) {
    int f  = wave * 2 + j;
    int tt = f >> 2, h = f & 3;
    int k  = 16 * tt + lq;
    f32x4 fv = fzero;
    if (k < NK_)
      fv = *(const f32x4*)(K + ((size_t)b * NK_ + k) * DM_ + 16 * h + 4 * quad);
    ((half4_t*)&lds_kf[h][lane])[tt] = cvt4(fv * KSCALE);
  }

  // ---- VW^T fragments for dt = wave (8 prologue MFMAs) ----
  {
    half4_t af[8];
    #pragma unroll
    for (int s = 0; s < 8; ++s) {
      int k = 16 * (s & 1) + lq, h = s >> 1;
      f32x4 f = fzero;
      if (k < NK_)
        f = *(const f32x4*)(V + ((size_t)b * NK_ + k) * DM_ + 16 * h + 4 * quad);
      af[s] = cvt4(f);
    }
    half4_t bf[4];
    #pragma unroll
    for (int h = 0; h < 4; ++h) {
      f32x4 f = *(const f32x4*)(W + (16 * wave + lq) * DM_ + 16 * h + 4 * quad);
      bf[h] = cvt4(f);
    }
    #pragma unroll
    for (int s = 0; s < 8; ++s) {
      f32x4 m = __builtin_amdgcn_mfma_f32_16x16x16f16(af[s], bf[s >> 1],
                                                      fzero, 0, 0, 0);
      ((half4_t*)&lds_vw[s][wave >> 1][lane])[wave & 1] = cvt4(m);
    }
  }

  // ---- bias fragments for the epilogue ----
  f32x4 bias[4];
  #pragma unroll
  for (int dt = 0; dt < 4; ++dt)
    bias[dt] = *(const f32x4*)(bout + 16 * dt + 4 * quad);

  __syncthreads();

  // ---- main loop ----
  #pragma unroll
  for (int it = 0; it < ITERS; ++it) {
    int q0 = (w + it * 256) * 16;

    // stage current Q tile -> LDS (swizzled); lane l holds (row 4j+quad, cb lq)
    #pragma unroll
    for (int j = 0; j < 4; ++j) {
      int row = 4 * j + quad;
      stg[wave][row][lq ^ (row & 7)] = qst[j];
    }

    // issue next tile's lane-contiguous loads (consumed by next iter's stage)
    if (it + 1 < ITERS) {
      const float* nb =
          Q + ((size_t)b * NQ_ + (size_t)(w + (it + 1) * 256) * 16) * DM_;
      #pragma unroll
      for (int j = 0; j < 4; ++j)
        qst[j] = *(const f32x4*)(nb + j * 256 + lane * 4);
    }

    // fragment reads: lane(lq,quad) h -> (row lq, cb 4h+quad)
    half4_t qf[4];
    #pragma unroll
    for (int h = 0; h < 4; ++h) {
      f32x4 qv = stg[wave][lq][(4 * h + quad) ^ (lq & 7)];
      qf[h] = cvt4(qv);
    }

    // GEMM1 + per-head softmax (log2-domain scores -> exp2)
    half4_t pf[8];
    #pragma unroll
    for (int h = 0; h < 4; ++h) {
      half8_t kk = lds_kf[h][lane];
      half4_t k0 = __builtin_shufflevector(kk, kk, 0, 1, 2, 3);
      half4_t k1 = __builtin_shufflevector(kk, kk, 4, 5, 6, 7);
      f32x4 c0 = __builtin_amdgcn_mfma_f32_16x16x16f16(k0, qf[h], cbias[0], 0, 0, 0);
      f32x4 c1 = __builtin_amdgcn_mfma_f32_16x16x16f16(k1, qf[h], cbias[1], 0, 0, 0);
      f32x4 e0, e1;
      #pragma unroll
      for (int r = 0; r < 4; ++r) {
        e0[r] = __builtin_amdgcn_exp2f(c0[r]);
        e1[r] = __builtin_amdgcn_exp2f(c1[r]);
      }
      float sum = (e0[0] + e0[1]) + (e0[2] + e0[3]) +
                  (e1[0] + e1[1]) + (e1[2] + e1[3]);
      sum += __shfl_xor(sum, 16);
      sum += __shfl_xor(sum, 32);
      float inv = (sum > 0.f) ? __builtin_amdgcn_rcpf(sum) : 0.f;
      pf[2 * h + 0] = cvt4(e0 * inv);
      pf[2 * h + 1] = cvt4(e1 * inv);
    }

    // GEMM2; VW^T frags streamed from LDS (2x ds_read_b128 per s)
    f32x4 acc[4] = {fzero, fzero, fzero, fzero};
    #pragma unroll
    for (int s = 0; s < 8; ++s) {
      half8_t v01 = lds_vw[s][0][lane];
      half8_t v23 = lds_vw[s][1][lane];
      half4_t a0 = __builtin_shufflevector(v01, v01, 0, 1, 2, 3);
      half4_t a1 = __builtin_shufflevector(v01, v01, 4, 5, 6, 7);
      half4_t a2 = __builtin_shufflevector(v23, v23, 0, 1, 2, 3);
      half4_t a3 = __builtin_shufflevector(v23, v23, 4, 5, 6, 7);
      acc[0] = __builtin_amdgcn_mfma_f32_16x16x16f16(a0, pf[s], acc[0], 0, 0, 0);
      acc[1] = __builtin_amdgcn_mfma_f32_16x16x16f16(a1, pf[s], acc[1], 0, 0, 0);
      acc[2] = __builtin_amdgcn_mfma_f32_16x16x16f16(a2, pf[s], acc[2], 0, 0, 0);
      acc[3] = __builtin_amdgcn_mfma_f32_16x16x16f16(a3, pf[s], acc[3], 0, 0, 0);
    }

    // epilogue: acc frags -> LDS (bias folded) -> lane-contiguous stores
    #pragma unroll
    for (int dt = 0; dt < 4; ++dt)
      stg[wave][lq][(4 * dt + quad) ^ (lq & 7)] = acc[dt] + bias[dt];

    float* ob = out + ((size_t)b * NQ_ + q0) * DM_;
    #pragma unroll
    for (int j = 0; j < 4; ++j) {
      int row = 4 * j + quad;
      f32x4 ov = stg[wave][row][lq ^ (row & 7)];
      *(f32x4*)(ob + j * 256 + lane * 4) = ov;
    }
  }
}

extern "C" void kernel_launch(void* const* d_in, const int* in_sizes, int n_in,
                              void* d_out, int out_size, void* d_ws, size_t ws_size,
                              hipStream_t stream) {
  const float*         Q    = (const float*)d_in[0];
  const float*         K    = (const float*)d_in[1];
  const float*         V    = (const float*)d_in[2];
  const unsigned char* mask = (const unsigned char*)d_in[3];
  const float*         W    = (const float*)d_in[4];
  const float*         bo   = (const float*)d_in[5];
  float*               out  = (float*)d_out;

  hipLaunchKernelGGL(attn, dim3(B_ * BLK_PER_B), dim3(256), 0, stream,
                     Q, K, V, mask, W, bo, out);
}